// Round 1
// baseline (125.739 us; speedup 1.0000x reference)
//
#include <hip/hip_runtime.h>
#include <hip/hip_bf16.h>
#include <math.h>

#define NQ 1024
#define BS 16
#define NC 256
#define NPRED (BS*NQ)   // 16384 pred boxes
#define MT 1024         // targets
#define GEPS 1e-6f

__device__ __forceinline__ float rcp_fast(float x) { return __builtin_amdgcn_rcpf(x); }

// ---------------- Kernel 1: preprocess ----------------
// blocks [0, 4096): softmax row stats (4 rows/block, one wave per row)
// blocks [4096, 4164): box extents (one box per thread; preds then tgts)
__global__ __launch_bounds__(256) void prep_kernel(
    const float* __restrict__ logits,     // [NPRED, NC]
    const float* __restrict__ pcorners,   // [NPRED, 8, 3]
    const float* __restrict__ tcorners,   // [MT, 8, 3]
    float* __restrict__ rowstat,          // [NPRED, 2] {rowmax, 1/sumexp}
    float* __restrict__ pext,             // [NPRED, 8] {mn0,mn1,mn2,mx0,mx1,mx2,vol,pad}
    float* __restrict__ text)             // [MT, 8]
{
    int t = threadIdx.x;
    int blk = blockIdx.x;
    if (blk < NPRED/4) {
        int wave = t >> 6, lane = t & 63;
        int row = blk*4 + wave;
        const float4 v = *(const float4*)(logits + (size_t)row*NC + lane*4);
        float mx = fmaxf(fmaxf(v.x, v.y), fmaxf(v.z, v.w));
        #pragma unroll
        for (int s = 1; s < 64; s <<= 1) mx = fmaxf(mx, __shfl_xor(mx, s));
        float e = __expf(v.x - mx) + __expf(v.y - mx) + __expf(v.z - mx) + __expf(v.w - mx);
        #pragma unroll
        for (int s = 1; s < 64; s <<= 1) e += __shfl_xor(e, s);
        if (lane == 0) {
            rowstat[row*2+0] = mx;
            rowstat[row*2+1] = 1.0f / e;
        }
    } else {
        int b = (blk - NPRED/4)*256 + t;
        const float* src; float* dst; int idx;
        if (b < NPRED)            { src = pcorners; dst = pext; idx = b; }
        else if (b < NPRED + MT)  { src = tcorners; dst = text; idx = b - NPRED; }
        else return;
        float buf[24];
        const float4* s4 = (const float4*)(src + (size_t)idx*24);
        #pragma unroll
        for (int i = 0; i < 6; ++i) *(float4*)&buf[i*4] = s4[i];
        float mn0 = buf[0], mn1 = buf[1], mn2 = buf[2];
        float mx0 = mn0, mx1 = mn1, mx2 = mn2;
        #pragma unroll
        for (int c = 1; c < 8; ++c) {
            mn0 = fminf(mn0, buf[c*3+0]); mx0 = fmaxf(mx0, buf[c*3+0]);
            mn1 = fminf(mn1, buf[c*3+1]); mx1 = fmaxf(mx1, buf[c*3+1]);
            mn2 = fminf(mn2, buf[c*3+2]); mx2 = fmaxf(mx2, buf[c*3+2]);
        }
        float vol = (mx0-mn0)*(mx1-mn1)*(mx2-mn2);
        *(float4*)(dst + (size_t)idx*8)     = make_float4(mn0, mn1, mn2, mx0);
        *(float4*)(dst + (size_t)idx*8 + 4) = make_float4(mx1, mx2, vol, 0.0f);
    }
}

// ---------------- Kernel 2: pairwise cost ----------------
// block = 16 n-rows x 256 m-cols. 4096 blocks (1024 n-tiles x 4 m-tiles).
// Per lane: 4 consecutive m's in registers; wave w handles rows w*4..w*4+3.
__global__ __launch_bounds__(256) void cost_kernel(
    const float* __restrict__ logits,   // [NPRED, NC]
    const float* __restrict__ pboxes,   // [NPRED, 6]
    const int*   __restrict__ tlabels,  // [MT]
    const float* __restrict__ tboxes,   // [MT, 6]
    const float* __restrict__ rowstat,  // [NPRED, 2]
    const float* __restrict__ pext,     // [NPRED, 8]
    const float* __restrict__ text,     // [MT, 8]
    float* __restrict__ out)            // [NPRED, MT]
{
    __shared__ float sProb[16][NC];
    int t = threadIdx.x;
    int mt = blockIdx.x & 3;
    int nt = blockIdx.x >> 2;
    int n_base = nt * 16;
    int m_base = mt * 256;

    // Fill prob tile: sProb[r][c] = softmax(logits[n_base+r])[c]
    #pragma unroll
    for (int r = 0; r < 16; ++r) {
        int row = n_base + r;
        float mx = rowstat[row*2+0];
        float rs = rowstat[row*2+1];
        float lg = logits[(size_t)row*NC + t];
        sProb[r][t] = __expf(lg - mx) * rs;
    }

    int lane = t & 63;
    int wave = t >> 6;
    int m0 = m_base + lane*4;

    // Per-lane target data in registers (4 m's)
    float4 ea[4], eb[4];
    float tb[4][6];
    int lb[4];
    #pragma unroll
    for (int j = 0; j < 4; ++j) {
        int m = m0 + j;
        ea[j] = *(const float4*)(text + (size_t)m*8);
        eb[j] = *(const float4*)(text + (size_t)m*8 + 4);
        float2 b0 = *(const float2*)(tboxes + (size_t)m*6);
        float2 b1 = *(const float2*)(tboxes + (size_t)m*6 + 2);
        float2 b2 = *(const float2*)(tboxes + (size_t)m*6 + 4);
        tb[j][0]=b0.x; tb[j][1]=b0.y; tb[j][2]=b1.x; tb[j][3]=b1.y; tb[j][4]=b2.x; tb[j][5]=b2.y;
        lb[j] = tlabels[m];
    }
    __syncthreads();

    #pragma unroll
    for (int i = 0; i < 4; ++i) {
        int r = wave*4 + i;
        int n = n_base + r;
        // wave-uniform pred data (L1 broadcast)
        float4 p0 = *(const float4*)(pext + (size_t)n*8);
        float4 p1 = *(const float4*)(pext + (size_t)n*8 + 4);
        float pmn0=p0.x, pmn1=p0.y, pmn2=p0.z;
        float pmx0=p0.w, pmx1=p1.x, pmx2=p1.y, vp=p1.z;
        float pb[6];
        #pragma unroll
        for (int k = 0; k < 6; ++k) pb[k] = pboxes[(size_t)n*6 + k];

        float rr[4];
        #pragma unroll
        for (int j = 0; j < 4; ++j) {
            float tmn0=ea[j].x, tmn1=ea[j].y, tmn2=ea[j].z, tmx0=ea[j].w;
            float tmx1=eb[j].x, tmx2=eb[j].y, vt=eb[j].z;
            float dx = fminf(pmx0,tmx0) - fmaxf(pmn0,tmn0); dx = fmaxf(dx, 0.0f);
            float dy = fminf(pmx1,tmx1) - fmaxf(pmn1,tmn1); dy = fmaxf(dy, 0.0f);
            float dz = fminf(pmx2,tmx2) - fmaxf(pmn2,tmn2); dz = fmaxf(dz, 0.0f);
            float inter = dx*dy*dz;
            float uni = vp + vt - inter;
            float ex = fmaxf(pmx0,tmx0) - fminf(pmn0,tmn0);
            float ey = fmaxf(pmx1,tmx1) - fminf(pmn1,tmn1);
            float ez = fmaxf(pmx2,tmx2) - fminf(pmn2,tmn2);
            float enc = ex*ey*ez;
            float iou  = inter * rcp_fast(uni + GEPS);
            float giou = iou - (enc - uni) * rcp_fast(enc + GEPS);
            float l1 = fabsf(pb[0]-tb[j][0]) + fabsf(pb[1]-tb[j][1]) + fabsf(pb[2]-tb[j][2])
                     + fabsf(pb[3]-tb[j][3]) + fabsf(pb[4]-tb[j][4]) + fabsf(pb[5]-tb[j][5]);
            float prob = sProb[r][lb[j]];
            rr[j] = l1 - prob - giou;
        }
        float4 res = make_float4(rr[0], rr[1], rr[2], rr[3]);
        *(float4*)(out + (size_t)n*MT + m0) = res;
    }
}

extern "C" void kernel_launch(void* const* d_in, const int* in_sizes, int n_in,
                              void* d_out, int out_size, void* d_ws, size_t ws_size,
                              hipStream_t stream) {
    const float* logits   = (const float*)d_in[0];  // [16,1024,256]
    const float* pboxes   = (const float*)d_in[1];  // [16,1024,6]
    const float* pcorners = (const float*)d_in[2];  // [16,1024,8,3]
    const int*   tlabels  = (const int*)d_in[3];    // [1024]
    const float* tboxes   = (const float*)d_in[4];  // [1024,6]
    const float* tcorners = (const float*)d_in[5];  // [1024,8,3]
    float* out = (float*)d_out;

    float* ws = (float*)d_ws;
    float* rowstat = ws;                       // 16384*2   = 32768 floats
    float* pext    = ws + 32768;               // 16384*8   = 131072 floats
    float* text    = ws + 32768 + 131072;      // 1024*8    = 8192 floats
    // total ws use: 688,128 bytes

    int prep_blocks = NPRED/4 + (NPRED + MT + 255)/256;   // 4096 + 68
    prep_kernel<<<prep_blocks, 256, 0, stream>>>(logits, pcorners, tcorners, rowstat, pext, text);
    cost_kernel<<<4096, 256, 0, stream>>>(logits, pboxes, tlabels, tboxes, rowstat, pext, text, out);
}

// Round 2
// 115.540 us; speedup vs baseline: 1.0883x; 1.0883x over previous
//
#include <hip/hip_runtime.h>
#include <hip/hip_bf16.h>
#include <math.h>

#define NQ 1024
#define BS 16
#define NC 256
#define NPRED (BS*NQ)   // 16384 pred boxes
#define MT 1024         // targets
#define GEPS 1e-6f

__device__ __forceinline__ float rcp_fast(float x) { return __builtin_amdgcn_rcpf(x); }
__device__ __forceinline__ float rfl(float x) {
    return __int_as_float(__builtin_amdgcn_readfirstlane(__float_as_int(x)));
}

// ---------------- Kernel 1: preprocess ----------------
// blocks [0, 4096): softmax row offset (4 rows/block, one wave per row)
//   rowoff[row] = rowmax + ln(sum exp(l - rowmax));  prob = exp(l - rowoff)
// blocks [4096, 4164): box extents
//   preds -> pext[n*8]  = {mn0,mn1,mn2,mx0,mx1,mx2,vol,pad}
//   tgts  -> trec[m*16] = {mn0,mn1,mn2,mx0,mx1,mx2,vol,label_bits, b0..b5,pad,pad}
__global__ __launch_bounds__(256) void prep_kernel(
    const float* __restrict__ logits,     // [NPRED, NC]
    const float* __restrict__ pcorners,   // [NPRED, 8, 3]
    const float* __restrict__ tcorners,   // [MT, 8, 3]
    const int*   __restrict__ tlabels,    // [MT]
    const float* __restrict__ tboxes,     // [MT, 6]
    float* __restrict__ rowoff,           // [NPRED]
    float* __restrict__ pext,             // [NPRED, 8]
    float* __restrict__ trec)             // [MT, 16]
{
    int t = threadIdx.x;
    int blk = blockIdx.x;
    if (blk < NPRED/4) {
        int wave = t >> 6, lane = t & 63;
        int row = blk*4 + wave;
        const float4 v = *(const float4*)(logits + (size_t)row*NC + lane*4);
        float mx = fmaxf(fmaxf(v.x, v.y), fmaxf(v.z, v.w));
        #pragma unroll
        for (int s = 1; s < 64; s <<= 1) mx = fmaxf(mx, __shfl_xor(mx, s));
        float e = __expf(v.x - mx) + __expf(v.y - mx) + __expf(v.z - mx) + __expf(v.w - mx);
        #pragma unroll
        for (int s = 1; s < 64; s <<= 1) e += __shfl_xor(e, s);
        if (lane == 0) rowoff[row] = mx + __logf(e);
    } else {
        int b = (blk - NPRED/4)*256 + t;
        bool is_pred = (b < NPRED);
        if (b >= NPRED + MT) return;
        int idx = is_pred ? b : (b - NPRED);
        const float* src = is_pred ? pcorners : tcorners;
        float buf[24];
        const float4* s4 = (const float4*)(src + (size_t)idx*24);
        #pragma unroll
        for (int i = 0; i < 6; ++i) *(float4*)&buf[i*4] = s4[i];
        float mn0 = buf[0], mn1 = buf[1], mn2 = buf[2];
        float mx0 = mn0, mx1 = mn1, mx2 = mn2;
        #pragma unroll
        for (int c = 1; c < 8; ++c) {
            mn0 = fminf(mn0, buf[c*3+0]); mx0 = fmaxf(mx0, buf[c*3+0]);
            mn1 = fminf(mn1, buf[c*3+1]); mx1 = fmaxf(mx1, buf[c*3+1]);
            mn2 = fminf(mn2, buf[c*3+2]); mx2 = fmaxf(mx2, buf[c*3+2]);
        }
        float vol = (mx0-mn0)*(mx1-mn1)*(mx2-mn2);
        if (is_pred) {
            *(float4*)(pext + (size_t)idx*8)     = make_float4(mn0, mn1, mn2, mx0);
            *(float4*)(pext + (size_t)idx*8 + 4) = make_float4(mx1, mx2, vol, 0.0f);
        } else {
            float2 b0 = *(const float2*)(tboxes + (size_t)idx*6);
            float2 b1 = *(const float2*)(tboxes + (size_t)idx*6 + 2);
            float2 b2 = *(const float2*)(tboxes + (size_t)idx*6 + 4);
            float lbf = __int_as_float(tlabels[idx]);
            float* d = trec + (size_t)idx*16;
            *(float4*)(d)      = make_float4(mn0, mn1, mn2, mx0);
            *(float4*)(d + 4)  = make_float4(mx1, mx2, vol, lbf);
            *(float4*)(d + 8)  = make_float4(b0.x, b0.y, b1.x, b1.y);
            *(float4*)(d + 12) = make_float4(b2.x, b2.y, 0.0f, 0.0f);
        }
    }
}

// ---------------- Kernel 2: pairwise cost ----------------
// block = 16 n-rows x 512 m-cols. grid 2048 = 8 blocks/CU x 4 waves = 32 waves/CU.
// Wave w owns rows w*4..w*4+3 (pred data wave-uniform -> SGPRs via readfirstlane).
// Each lane handles 1 m per chunk, 8 chunks of 64 m.
__global__ __launch_bounds__(256) void cost_kernel(
    const float* __restrict__ logits,   // [NPRED, NC]
    const float* __restrict__ pboxes,   // [NPRED, 6]
    const float* __restrict__ rowoff,   // [NPRED]
    const float* __restrict__ pext,     // [NPRED, 8]
    const float* __restrict__ trec,     // [MT, 16]
    float* __restrict__ out)            // [NPRED, MT]
{
    __shared__ float sProb[16][NC];
    const int t = threadIdx.x;
    const int nt = blockIdx.x >> 1;
    const int mt = blockIdx.x & 1;
    const int n_base = nt * 16;
    const int m_base = mt * 512;

    // Fill prob tile: sProb[r][c] = exp(logits[row][c] - rowoff[row])
    #pragma unroll
    for (int r = 0; r < 16; ++r) {
        const int row = n_base + r;
        const float off = rowoff[row];
        sProb[r][t] = __expf(logits[(size_t)row*NC + t] - off);
    }

    const int lane = t & 63;
    const int wave = t >> 6;

    // Pred data for this wave's 4 rows -> SGPRs (wave-uniform)
    float smn[4][3], smx[4][3], svol[4], spb[4][6];
    #pragma unroll
    for (int i = 0; i < 4; ++i) {
        const int n = n_base + wave*4 + i;
        float4 a  = *(const float4*)(pext + (size_t)n*8);
        float4 b  = *(const float4*)(pext + (size_t)n*8 + 4);
        float2 c0 = *(const float2*)(pboxes + (size_t)n*6);
        float2 c1 = *(const float2*)(pboxes + (size_t)n*6 + 2);
        float2 c2 = *(const float2*)(pboxes + (size_t)n*6 + 4);
        smn[i][0]=rfl(a.x);  smn[i][1]=rfl(a.y);  smn[i][2]=rfl(a.z);
        smx[i][0]=rfl(a.w);  smx[i][1]=rfl(b.x);  smx[i][2]=rfl(b.y);
        svol[i]=rfl(b.z);
        spb[i][0]=rfl(c0.x); spb[i][1]=rfl(c0.y); spb[i][2]=rfl(c1.x);
        spb[i][3]=rfl(c1.y); spb[i][4]=rfl(c2.x); spb[i][5]=rfl(c2.y);
    }
    __syncthreads();

    const size_t out_row0 = (size_t)(n_base + wave*4) * MT;

    #pragma unroll 1
    for (int c = 0; c < 8; ++c) {
        const int m = m_base + c*64 + lane;
        const float* tr = trec + (size_t)m*16;
        float4 a  = *(const float4*)(tr);
        float4 b  = *(const float4*)(tr + 4);
        float4 d0 = *(const float4*)(tr + 8);
        float2 d1 = *(const float2*)(tr + 12);
        const float tmn0=a.x, tmn1=a.y, tmn2=a.z, tmx0=a.w;
        const float tmx1=b.x, tmx2=b.y, vt=b.z;
        const int lb = __float_as_int(b.w);

        float prv[4];
        #pragma unroll
        for (int i = 0; i < 4; ++i) prv[i] = sProb[wave*4+i][lb];

        #pragma unroll
        for (int i = 0; i < 4; ++i) {
            float dx = fminf(smx[i][0],tmx0) - fmaxf(smn[i][0],tmn0); dx = fmaxf(dx,0.f);
            float dy = fminf(smx[i][1],tmx1) - fmaxf(smn[i][1],tmn1); dy = fmaxf(dy,0.f);
            float dz = fminf(smx[i][2],tmx2) - fmaxf(smn[i][2],tmn2); dz = fmaxf(dz,0.f);
            float inter = dx*dy*dz;
            float uni   = svol[i] + vt - inter;
            float ex = fmaxf(smx[i][0],tmx0) - fminf(smn[i][0],tmn0);
            float ey = fmaxf(smx[i][1],tmx1) - fminf(smn[i][1],tmn1);
            float ez = fmaxf(smx[i][2],tmx2) - fminf(smn[i][2],tmn2);
            float enc = ex*ey*ez;
            float iou  = inter * rcp_fast(uni + GEPS);
            float giou = iou - (enc - uni) * rcp_fast(enc + GEPS);
            float l1 = fabsf(spb[i][0]-d0.x) + fabsf(spb[i][1]-d0.y) + fabsf(spb[i][2]-d0.z)
                     + fabsf(spb[i][3]-d0.w) + fabsf(spb[i][4]-d1.x) + fabsf(spb[i][5]-d1.y);
            out[out_row0 + (size_t)i*MT + m] = l1 - prv[i] - giou;
        }
    }
}

extern "C" void kernel_launch(void* const* d_in, const int* in_sizes, int n_in,
                              void* d_out, int out_size, void* d_ws, size_t ws_size,
                              hipStream_t stream) {
    const float* logits   = (const float*)d_in[0];  // [16,1024,256]
    const float* pboxes   = (const float*)d_in[1];  // [16,1024,6]
    const float* pcorners = (const float*)d_in[2];  // [16,1024,8,3]
    const int*   tlabels  = (const int*)d_in[3];    // [1024]
    const float* tboxes   = (const float*)d_in[4];  // [1024,6]
    const float* tcorners = (const float*)d_in[5];  // [1024,8,3]
    float* out = (float*)d_out;

    float* ws = (float*)d_ws;
    float* rowoff = ws;                        // 16384 floats
    float* pext   = ws + 16384;                // 16384*8 = 131072 floats
    float* trec   = ws + 16384 + 131072;       // 1024*16 = 16384 floats
    // total ws use: 655,360 bytes (< 688,128 proven safe in R1)

    int prep_blocks = NPRED/4 + (NPRED + MT + 255)/256;   // 4096 + 68
    prep_kernel<<<prep_blocks, 256, 0, stream>>>(logits, pcorners, tcorners,
                                                 tlabels, tboxes, rowoff, pext, trec);
    cost_kernel<<<2048, 256, 0, stream>>>(logits, pboxes, rowoff, pext, trec, out);
}